// Round 13
// baseline (82.795 us; speedup 1.0000x reference)
//
#include <hip/hip_runtime.h>

// CRF-RNN mean-field, 2 iterations, N=8192 (32x16x16), C=4.
// Spatial attention: exactly separable -> 3 dense 1-D convs (fp32, exact).
// Bilateral attention: N^2 via MFMA (16x16x32 bf16):
//   logits  S = mfma(A=F_j, B=F_i) hi/lo-split features, nh embedded =>
//             S is the complete exp2 argument (fp32-accurate, misses only lo.lo).
//   weights P = exp2(S) packed bf16 (v_cvt_pk_bf16_f32) -> per-wave LDS tile.
//   numer  += mfma(A=P[16i x 32j], B=SM[32j x 16c]) fp32 accum.
// r11 fixes vs r10: no unroll + launch_bounds(256,4) (r10 spilled at the 64-VGPR
// cap), cvt_pk packing (28 VALU -> 4), 1-deep prefetch, conv blocks first.

#define HH 32
#define WW 16
#define DDD 16
#define NN (HH * WW * DDD)    // 8192
#define KS 16                 // split-K over j
#define JCH (NN / KS)         // 512 j per block
#define CONVB 32
#define ITILB (NN / 64)       // 128 i-tiles (64 i per block = 4 waves x 16)
#define GB2 (ITILB * KS)      // 2048 bilat blocks
#define L2E 1.4426950408889634f
#define C18 (L2E / 18.0f)     // spatial: exp(-d^2/18) == exp2(-d^2*C18)
#define SQL2E 1.2011224087864498f   // sqrt(log2 e)
#define SB (SQL2E / 8.0f)     // THETA_ALPHA
#define SC (SQL2E / 0.5f)     // THETA_BETA

#if __has_builtin(__builtin_amdgcn_exp2f)
#define EXP2(x) __builtin_amdgcn_exp2f(x)
#else
#define EXP2(x) exp2f(x)
#endif

typedef __attribute__((ext_vector_type(8))) short bf16x8;
typedef __attribute__((ext_vector_type(4))) float f32x4;
#define MFMA16 __builtin_amdgcn_mfma_f32_16x16x32_bf16

__device__ __forceinline__ unsigned short f2bf(float x) {
    unsigned int u = __float_as_uint(x);
    return (unsigned short)((u + 0x7FFFu + ((u >> 16) & 1u)) >> 16);
}
__device__ __forceinline__ float bf2f(unsigned short b) {
    return __uint_as_float(((unsigned int)b) << 16);
}
__device__ __forceinline__ unsigned int pk(unsigned short a, unsigned short b) {
    return (unsigned int)a | ((unsigned int)b << 16);
}
__device__ __forceinline__ unsigned int cvtpk(float lo, float hi) {
    unsigned int r;
    asm("v_cvt_pk_bf16_f32 %0, %1, %2" : "=v"(r) : "v"(lo), "v"(hi));
    return r;
}

// One-time: MFMA feature tables (hi/lo split, nh embedded), sm0 = softmax(u).
// fq rows (A/j-side): v0=[hi_f, hi_nh, 1] v1=[lo_f, lo_nh, 0] v2=[hi_f, 0, 1] v3=0
// fk rows (B/i-side): v0=[hi_f, 1, hi_nh] v1=[hi_f, 1, 0] v2=[lo_f, 0, lo_nh] v3=0
// => sum over k-blocks: hi.hi + lo.hi + hi.lo + nh_j + nh_i  (misses only lo.lo)
__global__ __launch_bounds__(256) void prep(
    const float* __restrict__ u, const float* __restrict__ rgb,
    unsigned short* __restrict__ fq, unsigned short* __restrict__ fk,
    float* __restrict__ sm0, unsigned short* __restrict__ smT0)
{
    int i = blockIdx.x * 256 + threadIdx.x;
    int h = i >> 8, r = i & 255, w = r >> 4, d = r & 15;
    float f[6];
    f[0] = (float)(h + 1) * SB;
    f[1] = (float)(w + 1) * SB;
    f[2] = (float)(d + 1) * SB;
    f[3] = rgb[3 * i + 0] * SC;
    f[4] = rgb[3 * i + 1] * SC;
    f[5] = rgb[3 * i + 2] * SC;
    float nh = -0.5f * (f[0]*f[0] + f[1]*f[1] + f[2]*f[2] +
                        f[3]*f[3] + f[4]*f[4] + f[5]*f[5]);
    unsigned short hi[7], lo[7];
    #pragma unroll
    for (int k = 0; k < 6; ++k) {
        hi[k] = f2bf(f[k]);
        lo[k] = f2bf(f[k] - bf2f(hi[k]));
    }
    hi[6] = f2bf(nh);
    lo[6] = f2bf(nh - bf2f(hi[6]));
    const unsigned short one = 0x3F80;  // bf16(1.0)

    uint4* q4 = (uint4*)(fq + (size_t)i * 32);
    uint4* k4 = (uint4*)(fk + (size_t)i * 32);
    q4[0] = make_uint4(pk(hi[0],hi[1]), pk(hi[2],hi[3]), pk(hi[4],hi[5]), pk(hi[6],one));
    q4[1] = make_uint4(pk(lo[0],lo[1]), pk(lo[2],lo[3]), pk(lo[4],lo[5]), pk(lo[6],0));
    q4[2] = make_uint4(pk(hi[0],hi[1]), pk(hi[2],hi[3]), pk(hi[4],hi[5]), pk(0,one));
    q4[3] = make_uint4(0, 0, 0, 0);
    k4[0] = make_uint4(pk(hi[0],hi[1]), pk(hi[2],hi[3]), pk(hi[4],hi[5]), pk(one,hi[6]));
    k4[1] = make_uint4(pk(hi[0],hi[1]), pk(hi[2],hi[3]), pk(hi[4],hi[5]), pk(one,0));
    k4[2] = make_uint4(pk(lo[0],lo[1]), pk(lo[2],lo[3]), pk(lo[4],lo[5]), pk(0,lo[6]));
    k4[3] = make_uint4(0, 0, 0, 0);

    float4 q = ((const float4*)u)[i];
    float m = fmaxf(fmaxf(q.x, q.y), fmaxf(q.z, q.w));
    float e0 = EXP2((q.x - m) * L2E), e1 = EXP2((q.y - m) * L2E);
    float e2 = EXP2((q.z - m) * L2E), e3 = EXP2((q.w - m) * L2E);
    float rs = 1.0f / (e0 + e1 + e2 + e3);
    float s0 = e0 * rs, s1 = e1 * rs, s2 = e2 * rs, s3 = e3 * rs;
    ((float4*)sm0)[i] = make_float4(s0, s1, s2, s3);
    smT0[0 * NN + i] = f2bf(s0);
    smT0[1 * NN + i] = f2bf(s1);
    smT0[2 * NN + i] = f2bf(s2);
    smT0[3 * NN + i] = f2bf(s3);
}

// blocks [0,CONVB): spatial conv D,W. blocks [CONVB, CONVB+GB2): bilateral MFMA.
__global__ __launch_bounds__(256, 4) void fused(
    const float* __restrict__ sm,     // [N][4] f32 softmax (conv path)
    const unsigned short* __restrict__ smT,  // [4][N] bf16 softmax (PV B-operand)
    const unsigned short* __restrict__ fq,   // [N][4][8] bf16 A-side rows
    const unsigned short* __restrict__ fk,   // [N][4][8] bf16 B-side rows
    float* __restrict__ part,         // [KS][N*4]
    float* __restrict__ tmp)          // [N][4] d,w-convolved sm
{
    __shared__ float lds[2048];       // conv: A|B halves; bilat: 4 waves x 320 u32
    int tid = threadIdx.x;

    if (blockIdx.x >= CONVB) {
        int b = blockIdx.x - CONVB;
        int ibk = b >> 4;             // / KS
        int kc = b & (KS - 1);
        int wv = tid >> 6, lane = tid & 63;
        int lm = lane & 15, lg = lane >> 4;
        int i0 = ibk * 64 + wv * 16;
        int j0 = kc * JCH;

        const bf16x8* FQ = (const bf16x8*)fq;
        const bf16x8* FK = (const bf16x8*)fk;
        // B-operand (i-side): lane: col i = i0+lm, k-block variant lg
        bf16x8 Bf = FK[(size_t)(i0 + lm) * 4 + lg];
        // PV B-operand source: channel c = lm&3 (cols >=4 never stored)
        const unsigned short* smc = smT + (size_t)(lm & 3) * NN;

        unsigned int* P = (unsigned int*)lds + wv * 320;  // [16 rows][20 u32]
        f32x4 acc = {0.f, 0.f, 0.f, 0.f};
        const f32x4 zro = {0.f, 0.f, 0.f, 0.f};

        const int NIT = JCH / 32;     // 16
        bf16x8 A0 = FQ[(size_t)(j0 + lm) * 4 + lg];
        bf16x8 A1 = FQ[(size_t)(j0 + 16 + lm) * 4 + lg];
        bf16x8 Sf = *(const bf16x8*)(smc + j0 + 8 * lg);

        for (int s = 0; s < NIT; ++s) {
            int js = j0 + s * 32;
            bf16x8 A0n, A1n, Sfn;
            if (s + 1 < NIT) {        // 1-deep prefetch: hide HBM/L2 latency
                A0n = FQ[(size_t)(js + 32 + lm) * 4 + lg];
                A1n = FQ[(size_t)(js + 48 + lm) * 4 + lg];
                Sfn = *(const bf16x8*)(smc + js + 32 + 8 * lg);
            }
            // S = full exp2-argument logit tile (D[j][i]: col=lm=i, row j=4*lg+reg)
            f32x4 S0 = MFMA16(A0, Bf, zro, 0, 0, 0);
            f32x4 S1 = MFMA16(A1, Bf, zro, 0, 0, 0);
            uint2 w0, w1;
            w0.x = cvtpk(EXP2(S0[0]), EXP2(S0[1]));
            w0.y = cvtpk(EXP2(S0[2]), EXP2(S0[3]));
            w1.x = cvtpk(EXP2(S1[0]), EXP2(S1[1]));
            w1.y = cvtpk(EXP2(S1[2]), EXP2(S1[3]));
            // P lds tile [i-local 16][j-local 32] bf16, row stride 20 u32
            *(uint2*)(P + lm * 20 + 2 * lg)     = w0;   // j = 4*lg+0..3
            *(uint2*)(P + lm * 20 + 2 * lg + 8) = w1;   // j = 16+4*lg+0..3
            // PV: A lane: row i=lm, k j=8*lg+0..7 ; B lane: col c=lm, same j
            bf16x8 Pf = *(const bf16x8*)(P + lm * 20 + 4 * lg);
            acc = MFMA16(Pf, Sf, acc, 0, 0, 0);
            A0 = A0n; A1 = A1n; Sf = Sfn;
        }
        // acc: col c = lm (<4 valid), row i = i0 + 4*lg + reg
        if (lm < 4) {
            float* pp = part + (size_t)kc * (NN * 4);
            #pragma unroll
            for (int r = 0; r < 4; ++r)
                pp[(size_t)(i0 + 4 * lg + r) * 4 + lm] = acc[r];
        }
    } else {
        // ---------------- spatial conv D, conv W (fp32 exact) ----------------
        int h = blockIdx.x;
        int s = tid;                 // s = w*16 + d
        int i = h * 256 + s;

        float* A = lds;              // [256][4]
        float* B = lds + 1024;       // [256][4]
        *((float4*)(A + 4 * s)) = ((const float4*)sm)[i];
        __syncthreads();

        int w = s >> 4, d = s & 15;
        float t0 = 0, t1 = 0, t2 = 0, t3 = 0;
        #pragma unroll
        for (int dp = 0; dp < DDD; ++dp) {
            float dd = (float)(d - dp);
            float k = EXP2(-dd * dd * C18);
            const float4 v = *((const float4*)(A + 4 * (w * 16 + dp)));
            t0 = fmaf(k, v.x, t0); t1 = fmaf(k, v.y, t1);
            t2 = fmaf(k, v.z, t2); t3 = fmaf(k, v.w, t3);
        }
        *((float4*)(B + 4 * s)) = make_float4(t0, t1, t2, t3);
        __syncthreads();

        float u0 = 0, u1 = 0, u2 = 0, u3 = 0;
        #pragma unroll
        for (int wp = 0; wp < WW; ++wp) {
            float dw = (float)(w - wp);
            float k = EXP2(-dw * dw * C18);
            const float4 v = *((const float4*)(B + 4 * (wp * 16 + d)));
            u0 = fmaf(k, v.x, u0); u1 = fmaf(k, v.y, u1);
            u2 = fmaf(k, v.z, u2); u3 = fmaf(k, v.w, u3);
        }
        *((float4*)(tmp + 4 * i)) = make_float4(u0, u1, u2, u3);
    }
}

// 512 blocks x 256 thr. Block owns 64 idx (= 16 i x 4 c).
// Wave q sums 4 part slices + 8 hp of h-conv; LDS combine; threads 0..15:
// normalize + 4x4 matmuls + unary add -> qout, softmax -> smout (f32 + bf16 T).
__global__ __launch_bounds__(256) void reduce_finish(
    const float* __restrict__ part,  // [KS][N*4]
    const float* __restrict__ tmp,   // [N][4] d,w-convolved sm
    const float* __restrict__ u,
    const float* __restrict__ sk, const float* __restrict__ bk,
    const float* __restrict__ cm,
    float* __restrict__ qout,
    float* __restrict__ smout,
    unsigned short* __restrict__ smTout)
{
    int tid = threadIdx.x;
    int q = tid >> 6;                // wave 0..3
    int lane = tid & 63;
    int idx = blockIdx.x * 64 + lane;

    float bl = 0.0f;
    #pragma unroll
    for (int k = 0; k < KS / 4; ++k)
        bl += part[(size_t)(q * (KS / 4) + k) * (NN * 4) + idx];

    int i = idx >> 2;
    int h = i >> 8;
    int scid = idx & 1023;
    float sp = 0.0f;
    #pragma unroll
    for (int k = 0; k < 8; ++k) {
        int hp = q * 8 + k;
        float dh = (float)(h - hp);
        float kk = EXP2(-dh * dh * C18);
        sp = fmaf(kk, tmp[hp * 1024 + scid], sp);
    }

    __shared__ float Lb[4][64];
    __shared__ float Ls[4][64];
    Lb[q][lane] = bl;
    Ls[q][lane] = sp;
    __syncthreads();

    if (tid < 16) {
        float b4[4], s4[4];
        #pragma unroll
        for (int c = 0; c < 4; ++c) {
            int l = tid * 4 + c;
            b4[c] = Lb[0][l] + Lb[1][l] + Lb[2][l] + Lb[3][l];
            s4[c] = Ls[0][l] + Ls[1][l] + Ls[2][l] + Ls[3][l];
        }
        float rb = 1.0f / (b4[0] + b4[1] + b4[2] + b4[3]);
        float rs = 1.0f / (s4[0] + s4[1] + s4[2] + s4[3]);
        float bo[4], so[4];
        #pragma unroll
        for (int c = 0; c < 4; ++c) { bo[c] = b4[c] * rb; so[c] = s4[c] * rs; }
        float msg[4];
        #pragma unroll
        for (int c = 0; c < 4; ++c) {
            float m = 0.0f;
            #pragma unroll
            for (int d = 0; d < 4; ++d)
                m += sk[c * 4 + d] * so[d] + bk[c * 4 + d] * bo[d];
            msg[c] = m;
        }
        int ig = blockIdx.x * 16 + tid;
        float qv[4];
        #pragma unroll
        for (int c = 0; c < 4; ++c) {
            float pw = 0.0f;
            #pragma unroll
            for (int d = 0; d < 4; ++d) pw += cm[c * 4 + d] * msg[d];
            qv[c] = u[4 * ig + c] + pw;
        }
        *((float4*)(qout + 4 * ig)) = make_float4(qv[0], qv[1], qv[2], qv[3]);

        float mm = fmaxf(fmaxf(qv[0], qv[1]), fmaxf(qv[2], qv[3]));
        float e0 = EXP2((qv[0] - mm) * L2E), e1 = EXP2((qv[1] - mm) * L2E);
        float e2 = EXP2((qv[2] - mm) * L2E), e3 = EXP2((qv[3] - mm) * L2E);
        float er = 1.0f / (e0 + e1 + e2 + e3);
        float sv0 = e0 * er, sv1 = e1 * er, sv2 = e2 * er, sv3 = e3 * er;
        *((float4*)(smout + 4 * ig)) = make_float4(sv0, sv1, sv2, sv3);
        smTout[0 * NN + ig] = f2bf(sv0);
        smTout[1 * NN + ig] = f2bf(sv1);
        smTout[2 * NN + ig] = f2bf(sv2);
        smTout[3 * NN + ig] = f2bf(sv3);
    }
}

extern "C" void kernel_launch(void* const* d_in, const int* in_sizes, int n_in,
                              void* d_out, int out_size, void* d_ws, size_t ws_size,
                              hipStream_t stream)
{
    const float* u   = (const float*)d_in[0];
    const float* rgb = (const float*)d_in[1];
    const float* sk  = (const float*)d_in[2];
    const float* bk  = (const float*)d_in[3];
    const float* cm  = (const float*)d_in[4];
    float* out = (float*)d_out;

    // ws: part[KS][N*4] | tmp | smA | smB | qbuf (f32) || fq | fk | smTA | smTB (u16)
    float* part = (float*)d_ws;
    float* tmpP = part + (size_t)KS * NN * 4;
    float* smA  = tmpP + (size_t)NN * 4;
    float* smB  = smA  + (size_t)NN * 4;
    float* qbuf = smB  + (size_t)NN * 4;
    unsigned short* fq   = (unsigned short*)(qbuf + (size_t)NN * 4);
    unsigned short* fk   = fq + (size_t)NN * 32;
    unsigned short* smTA = fk + (size_t)NN * 32;
    unsigned short* smTB = smTA + (size_t)NN * 4;

    dim3 blk(256);
    dim3 gP(NN / 256);           // 32
    dim3 gF(CONVB + GB2);        // 32 + 2048
    dim3 gR(NN * 4 / 64);        // 512

    prep<<<gP, blk, 0, stream>>>(u, rgb, fq, fk, smA, smTA);
    // iteration 1 (q = u)
    fused<<<gF, blk, 0, stream>>>(smA, smTA, fq, fk, part, tmpP);
    reduce_finish<<<gR, blk, 0, stream>>>(part, tmpP, u, sk, bk, cm, qbuf, smB, smTB);
    // iteration 2
    fused<<<gF, blk, 0, stream>>>(smB, smTB, fq, fk, part, tmpP);
    reduce_finish<<<gR, blk, 0, stream>>>(part, tmpP, u, sk, bk, cm, out, smA, smTA);
}

// Round 14
// 69.447 us; speedup vs baseline: 1.1922x; 1.1922x over previous
//
#include <hip/hip_runtime.h>

// CRF-RNN mean-field, 2 iterations, N=8192 (32x16x16), C=4.
// Spatial attention: exactly separable -> 3 dense 1-D convs.
// Bilateral attention: N^2 scalar, LDS-broadcast-read-throughput optimized:
//   - measured r6 bilat ~25-28us == 1.57M ds_read_b128 x 12cyc / 256CU (m134)
//   - fix: R=4 i-rows/thread + 24B j-records (color+nj b128, bf16-sm b64);
//     j positions recomputed from index (gh block-uniform, gw per-16, gd incr.)
//   - whole 64-j chunk staged once per block -> ONE barrier, pure LDS+VALU loop.
// Dispatches: prep | fused(conv+bilat) | reduce_finish | fused | reduce_finish.

#define HH 32
#define WW 16
#define DDD 16
#define NN (HH * WW * DDD)    // 8192
#define KS 128                // split-K over j
#define JC (NN / KS)          // 64 j per block
#define CONVB 32
#define ITIL 8                // i-tiles (1024 rows each: 256 thr x 4 rows)
#define GB (ITIL * KS)        // 1024 bilat blocks
#define L2E 1.4426950408889634f
#define C18 (L2E / 18.0f)     // spatial: exp(-d^2/18) == exp2(-d^2*C18)
#define SQL2E 1.2011224087864498f   // sqrt(log2 e): feats pre-scaled so exp==exp2
#define SB (SQL2E / 8.0f)     // THETA_ALPHA
#define SC (SQL2E / 0.5f)     // THETA_BETA

#if __has_builtin(__builtin_amdgcn_exp2f)
#define EXP2(x) __builtin_amdgcn_exp2f(x)
#else
#define EXP2(x) exp2f(x)
#endif

__device__ __forceinline__ unsigned short f2bf(float x) {
    unsigned int u = __float_as_uint(x);
    return (unsigned short)((u + 0x7FFFu + ((u >> 16) & 1u)) >> 16);
}
__device__ __forceinline__ unsigned int pk2(unsigned short a, unsigned short b) {
    return (unsigned int)a | ((unsigned int)b << 16);
}
__device__ __forceinline__ float bfLO(unsigned int u) {   // low bf16 -> f32
    return __uint_as_float(u << 16);
}
__device__ __forceinline__ float bfHI(unsigned int u) {   // high bf16 -> f32
    return __uint_as_float(u & 0xFFFF0000u);
}

// One-time: cpk[i] = {c0,c1,c2, nj_full} (iteration-invariant; nj includes the
// position part), smb[i] = bf16x4-packed softmax(u).
__global__ __launch_bounds__(256) void prep(
    const float* __restrict__ u, const float* __restrict__ rgb,
    float4* __restrict__ cpk, uint2* __restrict__ smb)
{
    int i = blockIdx.x * 256 + threadIdx.x;
    int h = i >> 8, r = i & 255, w = r >> 4, d = r & 15;
    float fh = (float)(h + 1) * SB;
    float fw = (float)(w + 1) * SB;
    float fd = (float)(d + 1) * SB;
    float c0 = rgb[3 * i + 0] * SC;
    float c1 = rgb[3 * i + 1] * SC;
    float c2 = rgb[3 * i + 2] * SC;
    float nj = -0.5f * (fh * fh + fw * fw + fd * fd +
                        c0 * c0 + c1 * c1 + c2 * c2);
    cpk[i] = make_float4(c0, c1, c2, nj);

    float4 q = ((const float4*)u)[i];
    float m = fmaxf(fmaxf(q.x, q.y), fmaxf(q.z, q.w));
    float e0 = EXP2((q.x - m) * L2E), e1 = EXP2((q.y - m) * L2E);
    float e2 = EXP2((q.z - m) * L2E), e3 = EXP2((q.w - m) * L2E);
    float rs = 1.0f / (e0 + e1 + e2 + e3);
    smb[i] = make_uint2(pk2(f2bf(e0 * rs), f2bf(e1 * rs)),
                        pk2(f2bf(e2 * rs), f2bf(e3 * rs)));
}

// blocks [0,CONVB): spatial conv D,W on sm -> tmp. blocks [CONVB..): bilateral.
__global__ __launch_bounds__(256, 4) void fused(
    const uint2* __restrict__ smb,   // [N] bf16x4 softmax(q)
    const float4* __restrict__ cpk,  // [N] {c0,c1,c2,nj}
    float* __restrict__ part,        // [KS][N*4]
    float* __restrict__ tmp)         // [N][4] d,w-convolved sm (f32)
{
    __shared__ float lds[2048];      // conv: A|B halves (8KB); bilat: 1.5KB recs
    int tid = threadIdx.x;

    if (blockIdx.x >= CONVB) {
        // ---------------- bilateral N^2, 4 rows/thread ----------------
        int b = blockIdx.x - CONVB;
        int ib = b >> 7;                 // / KS -> 8 i-tiles
        int kc = b & (KS - 1);
        int i0 = ib * 1024 + tid;        // rows: i0 + 256r, r=0..3
        int j0 = kc * JC;

        float4* recs4 = (float4*)lds;          // [64] {c0,c1,c2,nj}
        uint2*  recs2 = (uint2*)(lds + 256);   // [64] bf16x4 sm

        if (tid < JC) {
            recs4[tid] = cpk[j0 + tid];
            recs2[tid] = smb[j0 + tid];
        }

        // i-side: 4 coalesced float4 loads; fold row constants
        float fw = (float)((tid >> 4) + 1) * SB;
        float fd = (float)((tid & 15) + 1) * SB;
        float gh = (float)((j0 >> 8) + 1) * SB;    // uniform per block
        float4 cp[4];
        float  K[4];
        #pragma unroll
        for (int r = 0; r < 4; ++r) {
            cp[r] = cpk[i0 + 256 * r];
            float fh = (float)(ib * 4 + r + 1) * SB;
            K[r] = cp[r].w + fh * gh;    // nh_i(full) + fh_i*gh_j
        }
        float acc[4][4];
        #pragma unroll
        for (int r = 0; r < 4; ++r)
            #pragma unroll
            for (int c = 0; c < 4; ++c) acc[r][c] = 0.0f;

        __syncthreads();                 // the only barrier

        for (int jw = 0; jw < 4; ++jw) {
            float gw = (float)(((kc & 3) * 4 + jw) + 1) * SB;
            #pragma unroll 8
            for (int jd = 0; jd < 16; ++jd) {
                int jj = jw * 16 + jd;
                float gd = (float)(jd + 1) * SB;
                float4 r4 = recs4[jj];
                uint2  r2 = recs2[jj];
                float gpos = fmaf(fw, gw, fmaf(fd, gd, r4.w));
                float sm0 = bfLO(r2.x), sm1 = bfHI(r2.x);
                float sm2 = bfLO(r2.y), sm3 = bfHI(r2.y);
                #pragma unroll
                for (int r = 0; r < 4; ++r) {
                    float g = fmaf(cp[r].x, r4.x, K[r]);
                    g = fmaf(cp[r].y, r4.y, g);
                    g = fmaf(cp[r].z, r4.z, g);
                    g += gpos;
                    float wgt = EXP2(g);
                    acc[r][0] = fmaf(wgt, sm0, acc[r][0]);
                    acc[r][1] = fmaf(wgt, sm1, acc[r][1]);
                    acc[r][2] = fmaf(wgt, sm2, acc[r][2]);
                    acc[r][3] = fmaf(wgt, sm3, acc[r][3]);
                }
            }
        }

        float4* pp = (float4*)(part + (size_t)kc * (NN * 4));
        #pragma unroll
        for (int r = 0; r < 4; ++r)
            pp[i0 + 256 * r] = make_float4(acc[r][0], acc[r][1], acc[r][2], acc[r][3]);
    } else {
        // ---------------- spatial conv D, conv W ----------------
        int h = blockIdx.x;
        int s = tid;                 // s = w*16 + d
        int i = h * 256 + s;

        uint2 sb = smb[i];
        float* A = lds;              // [256][4]
        float* B = lds + 1024;       // [256][4]
        *((float4*)(A + 4 * s)) = make_float4(bfLO(sb.x), bfHI(sb.x),
                                              bfLO(sb.y), bfHI(sb.y));
        __syncthreads();

        int w = s >> 4, d = s & 15;
        float t0 = 0, t1 = 0, t2 = 0, t3 = 0;
        #pragma unroll
        for (int dp = 0; dp < DDD; ++dp) {
            float dd = (float)(d - dp);
            float k = EXP2(-dd * dd * C18);
            const float4 v = *((const float4*)(A + 4 * (w * 16 + dp)));
            t0 = fmaf(k, v.x, t0); t1 = fmaf(k, v.y, t1);
            t2 = fmaf(k, v.z, t2); t3 = fmaf(k, v.w, t3);
        }
        *((float4*)(B + 4 * s)) = make_float4(t0, t1, t2, t3);
        __syncthreads();

        float u0 = 0, u1 = 0, u2 = 0, u3 = 0;
        #pragma unroll
        for (int wp = 0; wp < WW; ++wp) {
            float dw = (float)(w - wp);
            float k = EXP2(-dw * dw * C18);
            const float4 v = *((const float4*)(B + 4 * (wp * 16 + d)));
            u0 = fmaf(k, v.x, u0); u1 = fmaf(k, v.y, u1);
            u2 = fmaf(k, v.z, u2); u3 = fmaf(k, v.w, u3);
        }
        *((float4*)(tmp + 4 * i)) = make_float4(u0, u1, u2, u3);
    }
}

// 512 blocks x 256 thr. Block owns 64 idx (= 16 i x 4 c).
// Wave q sums part slices [q*32, q*32+32) + 8 hp of h-conv; LDS combine;
// threads 0..15: normalize + 4x4 matmuls + unary add -> qout, softmax -> smbOut.
__global__ __launch_bounds__(256) void reduce_finish(
    const float* __restrict__ part,  // [KS][N*4]
    const float* __restrict__ tmp,   // [N][4] d,w-convolved sm
    const float* __restrict__ u,
    const float* __restrict__ sk, const float* __restrict__ bk,
    const float* __restrict__ cm,
    float* __restrict__ qout,
    uint2* __restrict__ smbOut)      // bf16x4 softmax(qout) for next iteration
{
    int tid = threadIdx.x;
    int q = tid >> 6;                // wave 0..3
    int lane = tid & 63;
    int idx = blockIdx.x * 64 + lane;

    float bl = 0.0f;
    #pragma unroll 8
    for (int k = 0; k < KS / 4; ++k)
        bl += part[(size_t)(q * (KS / 4) + k) * (NN * 4) + idx];

    int i = idx >> 2;
    int h = i >> 8;
    int scid = idx & 1023;
    float sp = 0.0f;
    #pragma unroll
    for (int k = 0; k < 8; ++k) {
        int hp = q * 8 + k;
        float dh = (float)(h - hp);
        float kk = EXP2(-dh * dh * C18);
        sp = fmaf(kk, tmp[hp * 1024 + scid], sp);
    }

    __shared__ float Lb[4][64];
    __shared__ float Ls[4][64];
    Lb[q][lane] = bl;
    Ls[q][lane] = sp;
    __syncthreads();

    if (tid < 16) {
        float b4[4], s4[4];
        #pragma unroll
        for (int c = 0; c < 4; ++c) {
            int l = tid * 4 + c;
            b4[c] = Lb[0][l] + Lb[1][l] + Lb[2][l] + Lb[3][l];
            s4[c] = Ls[0][l] + Ls[1][l] + Ls[2][l] + Ls[3][l];
        }
        float rb = 1.0f / (b4[0] + b4[1] + b4[2] + b4[3]);
        float rs = 1.0f / (s4[0] + s4[1] + s4[2] + s4[3]);
        float bo[4], so[4];
        #pragma unroll
        for (int c = 0; c < 4; ++c) { bo[c] = b4[c] * rb; so[c] = s4[c] * rs; }
        float msg[4];
        #pragma unroll
        for (int c = 0; c < 4; ++c) {
            float m = 0.0f;
            #pragma unroll
            for (int d = 0; d < 4; ++d)
                m += sk[c * 4 + d] * so[d] + bk[c * 4 + d] * bo[d];
            msg[c] = m;
        }
        int ig = blockIdx.x * 16 + tid;
        float qv[4];
        #pragma unroll
        for (int c = 0; c < 4; ++c) {
            float pw = 0.0f;
            #pragma unroll
            for (int d = 0; d < 4; ++d) pw += cm[c * 4 + d] * msg[d];
            qv[c] = u[4 * ig + c] + pw;
        }
        *((float4*)(qout + 4 * ig)) = make_float4(qv[0], qv[1], qv[2], qv[3]);

        float mm = fmaxf(fmaxf(qv[0], qv[1]), fmaxf(qv[2], qv[3]));
        float e0 = EXP2((qv[0] - mm) * L2E), e1 = EXP2((qv[1] - mm) * L2E);
        float e2 = EXP2((qv[2] - mm) * L2E), e3 = EXP2((qv[3] - mm) * L2E);
        float er = 1.0f / (e0 + e1 + e2 + e3);
        smbOut[ig] = make_uint2(pk2(f2bf(e0 * er), f2bf(e1 * er)),
                                pk2(f2bf(e2 * er), f2bf(e3 * er)));
    }
}

extern "C" void kernel_launch(void* const* d_in, const int* in_sizes, int n_in,
                              void* d_out, int out_size, void* d_ws, size_t ws_size,
                              hipStream_t stream)
{
    const float* u   = (const float*)d_in[0];
    const float* rgb = (const float*)d_in[1];
    const float* sk  = (const float*)d_in[2];
    const float* bk  = (const float*)d_in[3];
    const float* cm  = (const float*)d_in[4];
    float* out = (float*)d_out;

    // ws: part[KS][N*4] (16MB) | tmp[N*4] | qbuf[N*4] | cpk[N]f4 | smbA/B/D[N]u2
    float* part  = (float*)d_ws;
    float* tmpP  = part + (size_t)KS * NN * 4;
    float* qbuf  = tmpP + (size_t)NN * 4;
    float4* cpk  = (float4*)(qbuf + (size_t)NN * 4);
    uint2* smbA  = (uint2*)(cpk + NN);
    uint2* smbB  = smbA + NN;
    uint2* smbD  = smbB + NN;

    dim3 blk(256);
    dim3 gP(NN / 256);           // 32
    dim3 gF(CONVB + GB);         // 32 + 1024
    dim3 gR(NN * 4 / 64);        // 512

    prep<<<gP, blk, 0, stream>>>(u, rgb, cpk, smbA);
    // iteration 1 (q = u)
    fused<<<gF, blk, 0, stream>>>(smbA, cpk, part, tmpP);
    reduce_finish<<<gR, blk, 0, stream>>>(part, tmpP, u, sk, bk, cm, qbuf, smbB);
    // iteration 2
    fused<<<gF, blk, 0, stream>>>(smbB, cpk, part, tmpP);
    reduce_finish<<<gR, blk, 0, stream>>>(part, tmpP, u, sk, bk, cm, out, smbD);
}